// Round 7
// baseline (408.027 us; speedup 1.0000x reference)
//
#include <hip/hip_runtime.h>
#include <hip/hip_fp16.h>

// GCNConv via CSR-gather:
//   degree -> scan(+dis) -> fill8 (dst-range = XCD-local, nt streaming reads)
//   -> h' = fp16((x@W^T)*dis) -> gather (unroll-16, readlane broadcast, nt)
// N=100000, D=64, E=3200000

__global__ void degree_k(const int* __restrict__ ei, int* __restrict__ deg, int E) {
    int i = blockIdx.x * blockDim.x + threadIdx.x;
    int stride = gridDim.x * blockDim.x;
    for (int e = i; e < E; e += stride) {
        int d = __builtin_nontemporal_load(ei + E + e);
        atomicAdd(&deg[d], 1);
    }
}

// --- 3-pass exclusive scan of deg[0..N) -> rowptr; dis fused into pass 1 ---
__global__ void scan1_k(const int* __restrict__ deg, int* __restrict__ rowptr,
                        int* __restrict__ bsum, float* __restrict__ dis, int N) {
    __shared__ int tmp[256];
    int t = threadIdx.x;
    int g = blockIdx.x * 256 + t;
    int v = (g < N) ? deg[g] : 0;
    if (g < N) dis[g] = rsqrtf((float)(v + 1));   // +1 self-loop
    tmp[t] = v;
    __syncthreads();
#pragma unroll
    for (int off = 1; off < 256; off <<= 1) {
        int add = (t >= off) ? tmp[t - off] : 0;
        __syncthreads();
        tmp[t] += add;
        __syncthreads();
    }
    if (g < N) rowptr[g] = tmp[t] - v;
    if (t == 255) bsum[blockIdx.x] = tmp[255];
}

__global__ void scan2_k(int* __restrict__ bsum, int nb, int* __restrict__ rowptr,
                        int N, int E) {
    __shared__ int tmp[512];
    int t = threadIdx.x;
    int v = (t < nb) ? bsum[t] : 0;
    tmp[t] = v;
    __syncthreads();
#pragma unroll
    for (int off = 1; off < 512; off <<= 1) {
        int add = (t >= off) ? tmp[t - off] : 0;
        __syncthreads();
        tmp[t] += add;
        __syncthreads();
    }
    if (t < nb) bsum[t] = tmp[t] - v;
    if (t == 0) rowptr[N] = E;
}

__global__ void scan3_k(int* __restrict__ rowptr, int* __restrict__ cursor,
                        const int* __restrict__ bsum, int N) {
    int g = blockIdx.x * 256 + threadIdx.x;
    if (g < N) {
        int r = rowptr[g] + bsum[blockIdx.x];
        rowptr[g] = r;
        cursor[g] = r;
    }
}

// CSR fill, L2-local: block-group (blockIdx&7) -> XCD; group handles only dst
// in its 12500-node range. NT loads keep the edge stream out of L2 so the
// dirty cursor (50KB) + ent slice (~1.6MB) survive and write back full lines.
__global__ void fill8_k(const int* __restrict__ ei, int* __restrict__ cursor,
                        int* __restrict__ ent, int E, int nper) {
    int grp = blockIdx.x & 7;
    int lo = grp * nper;
    int hi = lo + nper;
    int i = (int)(blockIdx.x >> 3) * blockDim.x + threadIdx.x;
    int stride = (int)(gridDim.x >> 3) * blockDim.x;
    for (int e = i; e < E; e += stride) {
        int d = __builtin_nontemporal_load(ei + E + e);
        if (d >= lo && d < hi) {
            int s = __builtin_nontemporal_load(ei + e);
            int pos = atomicAdd(&cursor[d], 1);
            ent[pos] = s;   // normal store: accumulate in L2
        }
    }
}

// h' = fp16((x @ W^T) * dis[row]) : 4 rows/block, W staged in LDS [64][65].
__global__ void transform_k(const float* __restrict__ x, const float* __restrict__ W,
                            const float* __restrict__ dis, __half* __restrict__ h, int N) {
    __shared__ float Wl[64][65];
    __shared__ float xl[4][64];
    int t = threadIdx.x;
    for (int i = t; i < 64 * 64; i += 256) Wl[i >> 6][i & 63] = W[i];
    int r = t >> 6;
    int c = t & 63;
    int row = blockIdx.x * 4 + r;
    xl[r][c] = (row < N) ? __builtin_nontemporal_load(x + (long)row * 64 + c) : 0.0f;
    __syncthreads();
    float acc = 0.0f;
#pragma unroll
    for (int k = 0; k < 64; ++k) acc += xl[r][k] * Wl[c][k];
    if (row < N) h[(long)row * 64 + c] = __float2half(acc * dis[row]);
}

// One wave per node. Unroll-16: 16 readlane-broadcast src indices, 16
// independent 2B gathers in flight per wave. NT on streaming ent/out.
__global__ void gather_k(const int* __restrict__ rowptr, const int* __restrict__ ent,
                         const float* __restrict__ dis, const __half* __restrict__ h,
                         const float* __restrict__ b, float* __restrict__ out, int N) {
    int lane = threadIdx.x & 63;
    int n = blockIdx.x * (blockDim.x >> 6) + (threadIdx.x >> 6);
    if (n >= N) return;
    const __half* hl = h + lane;
    float acc = __half2float(hl[(long)n * 64]);   // self-loop (h' = h*dis)
    int beg = rowptr[n];
    int end = rowptr[n + 1];
    for (int i = beg; i < end; i += 64) {
        int m = end - i;
        if (m > 64) m = 64;
        int src = (lane < m) ? __builtin_nontemporal_load(ent + i + lane) : 0;
        int j = 0;
        for (; j + 16 <= m; j += 16) {
            int s0  = __builtin_amdgcn_readlane(src, j + 0);
            int s1  = __builtin_amdgcn_readlane(src, j + 1);
            int s2  = __builtin_amdgcn_readlane(src, j + 2);
            int s3  = __builtin_amdgcn_readlane(src, j + 3);
            int s4  = __builtin_amdgcn_readlane(src, j + 4);
            int s5  = __builtin_amdgcn_readlane(src, j + 5);
            int s6  = __builtin_amdgcn_readlane(src, j + 6);
            int s7  = __builtin_amdgcn_readlane(src, j + 7);
            int s8  = __builtin_amdgcn_readlane(src, j + 8);
            int s9  = __builtin_amdgcn_readlane(src, j + 9);
            int s10 = __builtin_amdgcn_readlane(src, j + 10);
            int s11 = __builtin_amdgcn_readlane(src, j + 11);
            int s12 = __builtin_amdgcn_readlane(src, j + 12);
            int s13 = __builtin_amdgcn_readlane(src, j + 13);
            int s14 = __builtin_amdgcn_readlane(src, j + 14);
            int s15 = __builtin_amdgcn_readlane(src, j + 15);
            float v0  = __half2float(hl[(long)s0  * 64]);
            float v1  = __half2float(hl[(long)s1  * 64]);
            float v2  = __half2float(hl[(long)s2  * 64]);
            float v3  = __half2float(hl[(long)s3  * 64]);
            float v4  = __half2float(hl[(long)s4  * 64]);
            float v5  = __half2float(hl[(long)s5  * 64]);
            float v6  = __half2float(hl[(long)s6  * 64]);
            float v7  = __half2float(hl[(long)s7  * 64]);
            float v8  = __half2float(hl[(long)s8  * 64]);
            float v9  = __half2float(hl[(long)s9  * 64]);
            float v10 = __half2float(hl[(long)s10 * 64]);
            float v11 = __half2float(hl[(long)s11 * 64]);
            float v12 = __half2float(hl[(long)s12 * 64]);
            float v13 = __half2float(hl[(long)s13 * 64]);
            float v14 = __half2float(hl[(long)s14 * 64]);
            float v15 = __half2float(hl[(long)s15 * 64]);
            acc += (((v0 + v1) + (v2 + v3)) + ((v4 + v5) + (v6 + v7)))
                 + (((v8 + v9) + (v10 + v11)) + ((v12 + v13) + (v14 + v15)));
        }
        for (; j + 4 <= m; j += 4) {
            int s0 = __builtin_amdgcn_readlane(src, j + 0);
            int s1 = __builtin_amdgcn_readlane(src, j + 1);
            int s2 = __builtin_amdgcn_readlane(src, j + 2);
            int s3 = __builtin_amdgcn_readlane(src, j + 3);
            float v0 = __half2float(hl[(long)s0 * 64]);
            float v1 = __half2float(hl[(long)s1 * 64]);
            float v2 = __half2float(hl[(long)s2 * 64]);
            float v3 = __half2float(hl[(long)s3 * 64]);
            acc += (v0 + v1) + (v2 + v3);
        }
        for (; j < m; ++j) {
            int s = __builtin_amdgcn_readlane(src, j);
            acc += __half2float(hl[(long)s * 64]);
        }
    }
    __builtin_nontemporal_store(acc * dis[n] + b[lane], out + (long)n * 64 + lane);
}

extern "C" void kernel_launch(void* const* d_in, const int* in_sizes, int n_in,
                              void* d_out, int out_size, void* d_ws, size_t ws_size,
                              hipStream_t stream) {
    const float* x  = (const float*)d_in[0];
    const int*   ei = (const int*)d_in[1];
    const float* W  = (const float*)d_in[2];
    const float* b  = (const float*)d_in[3];
    float* out = (float*)d_out;

    int N = in_sizes[0] / 64;
    int E = in_sizes[1] / 2;
    int nb = (N + 255) / 256;
    int nper = (N + 7) / 8;   // 12500 nodes per dst-range group

    char* ws = (char*)d_ws;
    size_t off = 0;
    auto alloc = [&](size_t bytes) { char* p = ws + off; off += (bytes + 255) & ~(size_t)255; return p; };
    int*    deg    = (int*)alloc((size_t)N * 4);
    float*  dis    = (float*)alloc((size_t)N * 4);
    int*    rowptr = (int*)alloc((size_t)(N + 1) * 4);
    int*    cursor = (int*)alloc((size_t)N * 4);
    int*    bsum   = (int*)alloc(512 * 4);
    int*    ent    = (int*)alloc((size_t)E * 4);
    __half* h      = (__half*)alloc((size_t)N * 64 * 2);

    hipMemsetAsync(deg, 0, (size_t)N * 4, stream);
    degree_k<<<2048, 256, 0, stream>>>(ei, deg, E);
    scan1_k<<<nb, 256, 0, stream>>>(deg, rowptr, bsum, dis, N);
    scan2_k<<<1, 512, 0, stream>>>(bsum, nb, rowptr, N, E);
    scan3_k<<<nb, 256, 0, stream>>>(rowptr, cursor, bsum, N);
    fill8_k<<<2048, 256, 0, stream>>>(ei, cursor, ent, E, nper);
    transform_k<<<(N + 3) / 4, 256, 0, stream>>>(x, W, dis, h, N);
    gather_k<<<(N + 3) / 4, 256, 0, stream>>>(rowptr, ent, dis, h, b, out, N);
}